// Round 11
// baseline (301.231 us; speedup 1.0000x reference)
//
#include <hip/hip_runtime.h>

// Problem constants (B=4, S=2048, E=1024, H=16, hd=64)
#define EMBED   1024
#define THREE_E 3072
#define NHEAD   16
#define HDIM    64
#define BATCH   4
#define SEQ     2048
#define MTOK    (BATCH * SEQ)   // 8192 tokens
#define QKW     2048            // compact QK plane row stride (16 heads x 128)

typedef __attribute__((ext_vector_type(8)))  _Float16 half8;
typedef __attribute__((ext_vector_type(4)))  _Float16 half4;
typedef __attribute__((ext_vector_type(4)))  float    f32x4;
typedef __attribute__((ext_vector_type(4)))  unsigned uint4v;

// Q pre-scale: 1/sqrt(hd) * log2(e) -> softmax runs in exp2 domain.
#define QSCALE 0.18033688011112042f

__device__ inline f32x4 mfma16(half8 a, half8 b, f32x4 c) {
    return __builtin_amdgcn_mfma_f32_16x16x32_f16(a, b, c, 0, 0, 0);
}

// bare v_exp_f32: input already in log2 domain (no pre-multiply like __expf)
__device__ inline float exp2x(float x) {
    float r;
    asm("v_exp_f32 %0, %1" : "=v"(r) : "v"(x));
    return r;
}
// pack 2 f32 -> 1 dword of 2 f16 (RTZ); low half = first arg
__device__ inline unsigned pk2(float a, float b) {
    return __builtin_bit_cast(unsigned, __builtin_amdgcn_cvt_pkrtz(a, b));
}

// async global -> LDS, 16B/lane (dest = wave-uniform base + lane*16)
__device__ inline void gld16(const void* g, void* l) {
    __builtin_amdgcn_global_load_lds(
        (const __attribute__((address_space(1))) unsigned*)g,
        (__attribute__((address_space(3))) unsigned*)l, 16, 0, 0);
}

// ---------------------------------------------------------------------------
// Fused pre-pass: fp32 -> fp16 for x, qkv_w, out_w in ONE launch.
// ---------------------------------------------------------------------------
__global__ __launch_bounds__(256) void tohi3_kernel(
    const float* __restrict__ x,  _Float16* __restrict__ xo,
    const float* __restrict__ w1, _Float16* __restrict__ w1o,
    const float* __restrict__ w2, _Float16* __restrict__ w2o)
{
    const int bid = blockIdx.x;
    const float* src; _Float16* dst; int base;
    if (bid < 8192)             { src = x;  dst = xo;  base = bid * 1024; }
    else if (bid < 8192 + 3072) { src = w1; dst = w1o; base = (bid - 8192) * 1024; }
    else                        { src = w2; dst = w2o; base = (bid - 11264) * 1024; }
    const int i = base + (threadIdx.x << 2);
    const float4 v = *(const float4*)(src + i);
    half4 h;
    h[0] = (_Float16)v.x; h[1] = (_Float16)v.y;
    h[2] = (_Float16)v.z; h[3] = (_Float16)v.w;
    *(half4*)(dst + i) = h;
}

// ---------------------------------------------------------------------------
// Phased big-tile fp16 MFMA GEMM (NT) v5 — occupancy-tuned.
// BM=128, BN=256, BK=32, 512 threads = 8 waves (2M x 4N), 64x64 per wave.
// v5 vs R10 (BK=64, 144KB LDS -> 1 block/CU, 2 waves/SIMD, MfmaUtil 22%,
// all pipes idle -> TLP-starved): BK=32, 3-slot LDS = 72KB -> 2 blocks/CU
// (4 waves/SIMD). Counted-vmcnt pipeline kept: tile t+2 staged during t,
// s_waitcnt vmcnt(3) at tile top (t's 3 loads retired, t+1's 3 in flight;
// never 0 in main loop). ONE barrier per tile:
//   - top-of-t barrier publishes "everyone's tile-t loads retired"
//     (each wave waited its own vmcnt(3) first);
//   - slot t+2 == slot t-1: its cross-wave ds_reads completed before
//     their consuming MFMAs (compiler lgkmcnt) which precede this
//     barrier; staging issued post-barrier -> no WAR.
//   OMODE=0: fp32 C.  OMODE=1: qkv writer — Q cols pre-scaled by QSCALE,
//   K cols -> fp16 plane [tok][2048], V cols -> V2 PV-native layout.
// ---------------------------------------------------------------------------
template<int OMODE>
__global__ __launch_bounds__(512, 4) void gemm_big(
    const _Float16* __restrict__ Ahi,
    const _Float16* __restrict__ Bhi,
    const float*  __restrict__ bias,
    float* __restrict__ Cf,
    _Float16* __restrict__ QKhi,
    _Float16* __restrict__ Vthi,
    int N, int K)
{
    __shared__ __align__(16) _Float16 sA[3][8][64][8];     // 24 KB
    __shared__ __align__(16) _Float16 sB[3][16][64][8];    // 48 KB

    const int tid  = threadIdx.x;
    const int w    = tid >> 6;
    const int lane = tid & 63;
    const int quad = lane >> 4;
    const int c    = lane & 15;
    const int wr   = w >> 2, wc = w & 3;

    const int gx   = gridDim.x;
    const int nwg  = gx * gridDim.y;
    const int lin0 = blockIdx.y * gx + blockIdx.x;
    const int wg   = (lin0 & 7) * (nwg >> 3) + (lin0 >> 3);
    const int m0   = (wg / gx) << 7;       // *128
    const int n0   = (wg % gx) << 8;       // *256

    f32x4 acc[4][4];
#pragma unroll
    for (int i = 0; i < 4; ++i)
#pragma unroll
        for (int j = 0; j < 4; ++j) acc[i][j] = (f32x4){0.f, 0.f, 0.f, 0.f};

    // staging: wave w loads A chunk w (rows m0+16w.., k quad*8) and
    // B chunks w, 8+w. 1 KB per gld16 (chunk = 16 rows x 32 k).
    const _Float16* ap  = Ahi + (size_t)(m0 + w * 16 + c) * K + quad * 8;
    const _Float16* bp0 = Bhi + (size_t)(n0 + w * 16 + c) * K + quad * 8;
    const _Float16* bp8 = Bhi + (size_t)(n0 + 128 + w * 16 + c) * K + quad * 8;

    auto stage = [&](int sl) {
        gld16(ap,  &sA[sl][w][0][0]);
        gld16(bp0, &sB[sl][w][0][0]);
        gld16(bp8, &sB[sl][8 + w][0][0]);
        ap += 32; bp0 += 32; bp8 += 32;
    };

    // prologue: tiles 0 and 1 staged (6 loads/wave outstanding)
    stage(0); stage(1);

    const int NT = K >> 5;
    int slot = 0;
    for (int t = 0; t < NT; ++t) {
        // counted wait: tile t's 3 loads retired, t+1's 3 stay in flight
        if (t + 1 < NT) { asm volatile("s_waitcnt vmcnt(3)" ::: "memory"); }
        else            { asm volatile("s_waitcnt vmcnt(0)" ::: "memory"); }
        __builtin_amdgcn_s_barrier();

        if (t + 2 < NT) {
            int ns = slot + 2; if (ns >= 3) ns -= 3;
            stage(ns);
        }

        half8 aH[4], bH[4];
#pragma unroll
        for (int fr = 0; fr < 4; ++fr)
            aH[fr] = *(const half8*)&sA[slot][wr * 4 + fr][lane][0];
#pragma unroll
        for (int fc = 0; fc < 4; ++fc)
            bH[fc] = *(const half8*)&sB[slot][wc * 4 + fc][lane][0];

        __builtin_amdgcn_s_setprio(1);
#pragma unroll
        for (int fr = 0; fr < 4; ++fr)
#pragma unroll
            for (int fc = 0; fc < 4; ++fc)
                acc[fr][fc] = mfma16(aH[fr], bH[fc], acc[fr][fc]);
        __builtin_amdgcn_s_setprio(0);

        slot = (slot == 2) ? 0 : slot + 1;
    }

    // epilogue: C/D layout row = quad*4+r, col = c (per 16x16 tile)
#pragma unroll
    for (int fc = 0; fc < 4; ++fc) {
        const int n  = n0 + wc * 64 + fc * 16 + c;
        const float bb = bias[n];
        const int h  = n / 192;
        const int rem = n - h * 192;
#pragma unroll
        for (int fr = 0; fr < 4; ++fr) {
            const int mb = m0 + wr * 64 + fr * 16 + (quad << 2);
            if constexpr (OMODE == 0) {
#pragma unroll
                for (int r = 0; r < 4; ++r)
                    Cf[(size_t)(mb + r) * N + n] = acc[fr][fc][r] + bb;
            } else {
                if (rem < 128) {
                    const size_t col = h * 128 + rem;
                    const float scale = (rem < 64) ? QSCALE : 1.0f;
#pragma unroll
                    for (int r = 0; r < 4; ++r)
                        QKhi[(size_t)(mb + r) * QKW + col] =
                            (_Float16)((acc[fr][fc][r] + bb) * scale);
                } else {
                    // V2 PV-native layout write (keys s..s+3, feature d)
                    const int d  = rem - 128;          // d = dbase + c, dbase%16==0
                    const int b  = mb >> 11;
                    const int s  = mb & 2047;          // s % 4 == 0
                    const int kt = s >> 6;
                    const int rs = s & 63;
                    const int gp = rs >> 5;
                    const int hf = (rs >> 4) & 1;
                    const int kq = (rs >> 2) & 3;
                    const int v  = d >> 4;
                    const int cl = d & 15;
                    half4 h4;
#pragma unroll
                    for (int r = 0; r < 4; ++r)
                        h4[r] = (_Float16)(acc[fr][fc][r] + bb);
                    const size_t off =
                        ((((size_t)(h * BATCH + b) * (SEQ / 64) + kt) * 8
                          + (v * 2 + gp)) * 512)
                        + (size_t)(kq * 16 + cl) * 8 + hf * 4;
                    *(half4*)(Vthi + off) = h4;
                }
            }
        }
    }
}

// ---------------------------------------------------------------------------
// MFMA flash attention v12 — unchanged from R10 (passing, <90 us).
// Full-rate PV via concat frags, PV-native V2 (conflict-free b128 reads),
// ones-MFMA l row-sums, max-free exp2 softmax, double-buffered staging.
// ---------------------------------------------------------------------------
__global__ __launch_bounds__(256, 4) void attn_mfma(
    const _Float16* __restrict__ qkhi,
    const _Float16* __restrict__ vthi,
    _Float16* __restrict__ attnf)
{
    __shared__ __align__(16) _Float16 Kf[2][8][512];    // chunk idx = u*2 + ks
    __shared__ __align__(16) _Float16 Vf[2][8][512];    // chunk idx = v*2 + gp

    const int tid  = threadIdx.x;
    const int w    = tid >> 6;
    const int lane = tid & 63;
    const int quad = lane >> 4;
    const int c    = lane & 15;

    const int lin = blockIdx.x;
    const int g   = lin & 7;               // assumed XCD id
    const int s   = lin >> 3;              // 0..127
    const int bh  = g * 8 + (s >> 4);      // 8 bh per XCD
    const int qt  = s & 15;                // 16 q-tiles of 128
    const int b   = bh >> 4, h = bh & 15;
    const int q0  = qt * 128;

    const size_t bSEQ  = (size_t)b * SEQ;
    const int    qcol  = h * 128;
    const int    kcol  = h * 128 + 64;

    // ---- preload Q fragments (B-operand): rows q0 + w*32 + t*16 + c ----
    half8 qh[2][2];
#pragma unroll
    for (int t = 0; t < 2; ++t) {
        const size_t row = (bSEQ + q0 + w * 32 + t * 16 + c) * QKW;
#pragma unroll
        for (int ks = 0; ks < 2; ++ks)
            qh[t][ks] = *(const half8*)(qkhi + row + qcol + ks * 32 + quad * 8);
    }

    f32x4 lacc[2];
    f32x4 oacc[4][2];                       // [v(d-tile)][t]: O^T rows d, col q=c
#pragma unroll
    for (int t = 0; t < 2; ++t) {
        lacc[t] = (f32x4){0.f, 0.f, 0.f, 0.f};
#pragma unroll
        for (int v = 0; v < 4; ++v) oacc[v][t] = (f32x4){0.f, 0.f, 0.f, 0.f};
    }

    const half8 one8 = {(_Float16)1.f, (_Float16)1.f, (_Float16)1.f, (_Float16)1.f,
                        (_Float16)1.f, (_Float16)1.f, (_Float16)1.f, (_Float16)1.f};

    // ---- loop-invariant staging pointers ----
    const int ku0 = w >> 1,       kks0 = w & 1;
    const int ku1 = (4 + w) >> 1, kks1 = (4 + w) & 1;
    const _Float16* kp0 = qkhi + (bSEQ + ku0 * 16 + c) * QKW + kcol + kks0 * 32 + quad * 8;
    const _Float16* kp1 = qkhi + (bSEQ + ku1 * 16 + c) * QKW + kcol + kks1 * 32 + quad * 8;
    // V2: per (h,b,kt) 8 chunks x 512 halves, fully linear staging
    const _Float16* vp0 = vthi + ((size_t)(h * BATCH + b) * (SEQ / 64)) * 4096
                               + (size_t)w * 512 + lane * 8;
    const _Float16* vp1 = vp0 + 4 * 512;

    auto stageKV = [&](int bfs) {
        gld16(kp0, &Kf[bfs][w][0]);
        gld16(kp1, &Kf[bfs][4 + w][0]);
        gld16(vp0, &Vf[bfs][w][0]);
        gld16(vp1, &Vf[bfs][4 + w][0]);
        kp0 += 64 * QKW; kp1 += 64 * QKW; vp0 += 4096; vp1 += 4096;
    };

    stageKV(0);
    int bf = 0;

    for (int kt = 0; kt < SEQ / 64; ++kt) {
        __syncthreads();                       // staged loads for bf complete
        if (kt + 1 < SEQ / 64) stageKV(bf ^ 1);   // prefetch next tile

        // ---- QK^T for BOTH q-tiles per kh chunk (kh read once, 8 b128) ----
        f32x4 sacc[2][4];
        __builtin_amdgcn_s_setprio(1);
#pragma unroll
        for (int u = 0; u < 4; ++u) {
            const half8 kh0 = *(const half8*)&Kf[bf][(u << 1) + 0][lane << 3];
            const half8 kh1 = *(const half8*)&Kf[bf][(u << 1) + 1][lane << 3];
#pragma unroll
            for (int t = 0; t < 2; ++t) {
                f32x4 a = (f32x4){0.f, 0.f, 0.f, 0.f};
                a = mfma16(kh0, qh[t][0], a);
                a = mfma16(kh1, qh[t][1], a);
                sacc[t][u] = a;
            }
        }
        __builtin_amdgcn_s_setprio(0);

        // ---- max-free softmax (exp2 domain): P = 2^s; pack into concat
        //      B-frags pb[t][gp] (elems 0-3 <- u=2gp, elems 4-7 <- u=2gp+1)
        half8 pb[2][2];
#pragma unroll
        for (int t = 0; t < 2; ++t)
#pragma unroll
            for (int gp = 0; gp < 2; ++gp) {
                uint4v wd;
#pragma unroll
                for (int hf = 0; hf < 2; ++hf) {
                    const int u = 2 * gp + hf;
                    const float p0 = exp2x(sacc[t][u][0]);
                    const float p1 = exp2x(sacc[t][u][1]);
                    const float p2 = exp2x(sacc[t][u][2]);
                    const float p3 = exp2x(sacc[t][u][3]);
                    if (hf == 0) { wd.x = pk2(p0, p1); wd.y = pk2(p2, p3); }
                    else         { wd.z = pk2(p0, p1); wd.w = pk2(p2, p3); }
                }
                pb[t][gp] = __builtin_bit_cast(half8, wd);
            }

        // ---- V concat A-frags: ONE b128 per (v,gp), conflict-free ----
        half8 vb[4][2];
#pragma unroll
        for (int v = 0; v < 4; ++v)
#pragma unroll
            for (int gp = 0; gp < 2; ++gp)
                vb[v][gp] = *(const half8*)&Vf[bf][(v << 1) + gp][lane << 3];

        // ---- PV (full-rate 16x16x32) + ones-MFMA l row-sums ----
        __builtin_amdgcn_s_setprio(1);
#pragma unroll
        for (int t = 0; t < 2; ++t) {
#pragma unroll
            for (int v = 0; v < 4; ++v) {
                f32x4 a = oacc[v][t];
                a = mfma16(vb[v][0], pb[t][0], a);
                a = mfma16(vb[v][1], pb[t][1], a);
                oacc[v][t] = a;
            }
            f32x4 l = lacc[t];
            l = mfma16(one8, pb[t][0], l);
            l = mfma16(one8, pb[t][1], l);
            lacc[t] = l;
        }
        __builtin_amdgcn_s_setprio(0);

        bf ^= 1;
    }

    // ---- epilogue: O^T /= l (all rows of lacc equal); write fp16 plane ----
#pragma unroll
    for (int t = 0; t < 2; ++t) {
        const float inv = 1.0f / lacc[t][0];
        const int tok = q0 + w * 32 + t * 16 + c;
#pragma unroll
        for (int v = 0; v < 4; ++v) {
            half4 o;
#pragma unroll
            for (int r = 0; r < 4; ++r) o[r] = (_Float16)(oacc[v][t][r] * inv);
            *(half4*)&attnf[(bSEQ + tok) * EMBED + h * HDIM + v * 16 + (quad << 2)] = o;
        }
    }
}

// ---------------------------------------------------------------------------
// Workspace (~76 MB of 128 MiB):
//   QK plane [8192][2048]             = 33.55 MB
//   V2 plane [16][4][32][8][512]      = 16.78 MB (PV-native chunks)
//   w1 hi    [3072][1024]             =  6.29 MB
//   w2 hi    [1024][1024]             =  2.10 MB
//   attn fp16 [8192][1024]            = 16.78 MB
// x hi plane lives in d_out (16.78 MB), dead before GEMM2 overwrites it.
// ---------------------------------------------------------------------------
extern "C" void kernel_launch(void* const* d_in, const int* in_sizes, int n_in,
                              void* d_out, int out_size, void* d_ws, size_t ws_size,
                              hipStream_t stream)
{
    const float* x     = (const float*)d_in[0];
    const float* qkv_w = (const float*)d_in[1];
    const float* qkv_b = (const float*)d_in[2];
    const float* out_w = (const float*)d_in[3];
    const float* out_b = (const float*)d_in[4];

    _Float16* qkhi  = (_Float16*)d_ws;
    _Float16* vthi  = qkhi  + (size_t)MTOK * QKW;
    _Float16* w1hi  = vthi  + (size_t)NHEAD * HDIM * BATCH * SEQ;
    _Float16* w2hi  = w1hi  + (size_t)THREE_E * EMBED;
    _Float16* attnf = w2hi  + (size_t)EMBED * EMBED;

    _Float16* xhi = (_Float16*)d_out;

    // fused fp32->fp16 pre-pass (single launch)
    tohi3_kernel<<<dim3(12288), 256, 0, stream>>>(x, xhi, qkv_w, w1hi, out_w, w2hi);

    // qkv = x @ qkv_w^T + qkv_b  -> QK plane (Q pre-scaled, exp2 domain) + V2 plane
    gemm_big<1><<<dim3(THREE_E / 256, MTOK / 128), 512, 0, stream>>>(
        xhi, w1hi, qkv_b, nullptr, qkhi, vthi, THREE_E, EMBED);

    // attention -> attn fp16 plane (1024 blocks, XCD-swizzled, 4 blocks/CU)
    attn_mfma<<<dim3(1024), 256, 0, stream>>>(qkhi, vthi, attnf);

    // out = attn @ out_w^T + out_b  -> fp32 d_out
    gemm_big<0><<<dim3(EMBED / 256, MTOK / 128), 512, 0, stream>>>(
        attnf, w2hi, out_b, (float*)d_out, nullptr, nullptr, EMBED, EMBED);
}

// Round 12
// 281.673 us; speedup vs baseline: 1.0694x; 1.0694x over previous
//
#include <hip/hip_runtime.h>

// Problem constants (B=4, S=2048, E=1024, H=16, hd=64)
#define EMBED   1024
#define THREE_E 3072
#define NHEAD   16
#define HDIM    64
#define BATCH   4
#define SEQ     2048
#define MTOK    (BATCH * SEQ)   // 8192 tokens
#define QKW     2048            // compact QK plane row stride (16 heads x 128)

typedef __attribute__((ext_vector_type(8)))  _Float16 half8;
typedef __attribute__((ext_vector_type(4)))  _Float16 half4;
typedef __attribute__((ext_vector_type(4)))  float    f32x4;
typedef __attribute__((ext_vector_type(4)))  unsigned uint4v;

// Q pre-scale: 1/sqrt(hd) * log2(e) -> softmax runs in exp2 domain.
#define QSCALE 0.18033688011112042f

__device__ inline f32x4 mfma16(half8 a, half8 b, f32x4 c) {
    return __builtin_amdgcn_mfma_f32_16x16x32_f16(a, b, c, 0, 0, 0);
}

// bare v_exp_f32: input already in log2 domain (no pre-multiply like __expf)
__device__ inline float exp2x(float x) {
    float r;
    asm("v_exp_f32 %0, %1" : "=v"(r) : "v"(x));
    return r;
}
// pack 2 f32 -> 1 dword of 2 f16 (RTZ); low half = first arg
__device__ inline unsigned pk2(float a, float b) {
    return __builtin_bit_cast(unsigned, __builtin_amdgcn_cvt_pkrtz(a, b));
}

// async global -> LDS, 16B/lane (dest = wave-uniform base + lane*16)
__device__ inline void gld16(const void* g, void* l) {
    __builtin_amdgcn_global_load_lds(
        (const __attribute__((address_space(1))) unsigned*)g,
        (__attribute__((address_space(3))) unsigned*)l, 16, 0, 0);
}

// ---------------------------------------------------------------------------
// Fused pre-pass: fp32 -> fp16 for x, qkv_w, out_w in ONE launch.
// ---------------------------------------------------------------------------
__global__ __launch_bounds__(256) void tohi3_kernel(
    const float* __restrict__ x,  _Float16* __restrict__ xo,
    const float* __restrict__ w1, _Float16* __restrict__ w1o,
    const float* __restrict__ w2, _Float16* __restrict__ w2o)
{
    const int bid = blockIdx.x;
    const float* src; _Float16* dst; int base;
    if (bid < 8192)             { src = x;  dst = xo;  base = bid * 1024; }
    else if (bid < 8192 + 3072) { src = w1; dst = w1o; base = (bid - 8192) * 1024; }
    else                        { src = w2; dst = w2o; base = (bid - 11264) * 1024; }
    const int i = base + (threadIdx.x << 2);
    const float4 v = *(const float4*)(src + i);
    half4 h;
    h[0] = (_Float16)v.x; h[1] = (_Float16)v.y;
    h[2] = (_Float16)v.z; h[3] = (_Float16)v.w;
    *(half4*)(dst + i) = h;
}

// ---------------------------------------------------------------------------
// Phased big-tile fp16 MFMA GEMM (NT) v6 — R10 structure + A-banded swizzle.
// BM=128, BN=256, BK=64, 8 waves; 3-slot LDS (144 KB), tile t+2 staged
// during t, counted s_waitcnt vmcnt(6) at tile top (never 0 in main loop).
// NEW (v6): XCD x owns a contiguous by-band (by = x*(gy/8) + s/gx,
// bx = s%gx). R10's round-robin swizzle scattered each XCD's blocks over
// ALL A row-tiles -> per-XCD A traffic 16.8 MB through a 4 MB L2
// (FETCH_SIZE 84 MB vs 23 MB inputs; staging delivery pinned at the
// ~11 B/cyc/CU memory ceiling -> MfmaUtil 22%). Banding gives concurrent
// blocks ~3 shared A-panels (0.8 MB, L2-resident); B streams once.
// Bijective: nwg%8==0 (768, 256); nwg/8 = (gy/8)*gx exactly.
//   OMODE=0: fp32 C.  OMODE=1: qkv writer — Q cols pre-scaled by QSCALE,
//   K cols -> fp16 plane [tok][2048], V cols -> V2 PV-native layout.
// ---------------------------------------------------------------------------
template<int OMODE>
__global__ __launch_bounds__(512, 2) void gemm_big(
    const _Float16* __restrict__ Ahi,
    const _Float16* __restrict__ Bhi,
    const float*  __restrict__ bias,
    float* __restrict__ Cf,
    _Float16* __restrict__ QKhi,
    _Float16* __restrict__ Vthi,
    int N, int K)
{
    __shared__ __align__(16) _Float16 sA[3][8][2][64][8];    // 48 KB
    __shared__ __align__(16) _Float16 sB[3][16][2][64][8];   // 96 KB

    const int tid  = threadIdx.x;
    const int w    = tid >> 6;
    const int lane = tid & 63;
    const int quad = lane >> 4;
    const int c    = lane & 15;
    const int wr   = w >> 2, wc = w & 3;

    // A-banded XCD swizzle: XCD = lin0%8 owns by in [x*gy/8, (x+1)*gy/8)
    const int gx   = gridDim.x;
    const int gy   = gridDim.y;
    const int lin0 = blockIdx.y * gx + blockIdx.x;
    const int xcd  = lin0 & 7;
    const int s    = lin0 >> 3;
    const int by   = xcd * (gy >> 3) + s / gx;
    const int bx   = s % gx;
    const int m0   = by << 7;              // *128
    const int n0   = bx << 8;              // *256

    f32x4 acc[4][4];
#pragma unroll
    for (int i = 0; i < 4; ++i)
#pragma unroll
        for (int j = 0; j < 4; ++j) acc[i][j] = (f32x4){0.f, 0.f, 0.f, 0.f};

    const int rg0 = w >> 1, ksb = w & 1;
    const size_t sK64 = (size_t)64 * K;
    const _Float16* ap = Ahi + (size_t)(m0 + rg0 * 16 + c) * K + ksb * 32 + quad * 8;
    const _Float16* bp = Bhi + (size_t)(n0 + rg0 * 16 + c) * K + ksb * 32 + quad * 8;

    auto stage_p0 = [&](int sl) {
        gld16(ap,            &sA[sl][rg0][ksb][0][0]);
        gld16(ap + sK64,     &sA[sl][4 + rg0][ksb][0][0]);
        gld16(bp,            &sB[sl][rg0][ksb][0][0]);
    };
    auto stage_p1 = [&](int sl) {
        gld16(bp + sK64,     &sB[sl][4 + rg0][ksb][0][0]);
        gld16(bp + 2 * sK64, &sB[sl][8 + rg0][ksb][0][0]);
        gld16(bp + 3 * sK64, &sB[sl][12 + rg0][ksb][0][0]);
        ap += 64; bp += 64;
    };

    stage_p0(0); stage_p1(0);
    stage_p0(1); stage_p1(1);

    const int NT = K >> 6;
    int slot = 0;
    for (int t = 0; t < NT; ++t) {
        if (t + 1 < NT) { asm volatile("s_waitcnt vmcnt(6)" ::: "memory"); }
        else            { asm volatile("s_waitcnt vmcnt(0)" ::: "memory"); }
        __builtin_amdgcn_s_barrier();

        const bool pre = (t + 2) < NT;
        int ns = slot + 2; if (ns >= 3) ns -= 3;

        half8 aH[4][2], bH[4][2];
#pragma unroll
        for (int fr = 0; fr < 4; ++fr)
#pragma unroll
            for (int ks = 0; ks < 2; ++ks)
                aH[fr][ks] = *(const half8*)&sA[slot][wr * 4 + fr][ks][lane][0];
#pragma unroll
        for (int fc = 0; fc < 2; ++fc)
#pragma unroll
            for (int ks = 0; ks < 2; ++ks)
                bH[fc][ks] = *(const half8*)&sB[slot][wc * 4 + fc][ks][lane][0];
        if (pre) stage_p0(ns);
        __builtin_amdgcn_s_setprio(1);
#pragma unroll
        for (int fr = 0; fr < 4; ++fr)
#pragma unroll
            for (int fc = 0; fc < 2; ++fc)
#pragma unroll
                for (int ks = 0; ks < 2; ++ks)
                    acc[fr][fc] = mfma16(aH[fr][ks], bH[fc][ks], acc[fr][fc]);
        __builtin_amdgcn_s_setprio(0);
        __builtin_amdgcn_s_barrier();

#pragma unroll
        for (int fc = 2; fc < 4; ++fc)
#pragma unroll
            for (int ks = 0; ks < 2; ++ks)
                bH[fc][ks] = *(const half8*)&sB[slot][wc * 4 + fc][ks][lane][0];
        if (pre) stage_p1(ns);
        __builtin_amdgcn_s_setprio(1);
#pragma unroll
        for (int fr = 0; fr < 4; ++fr)
#pragma unroll
            for (int fc = 2; fc < 4; ++fc)
#pragma unroll
                for (int ks = 0; ks < 2; ++ks)
                    acc[fr][fc] = mfma16(aH[fr][ks], bH[fc][ks], acc[fr][fc]);
        __builtin_amdgcn_s_setprio(0);

        slot = (slot == 2) ? 0 : slot + 1;
    }

    // epilogue: C/D layout row = quad*4+r, col = c (per 16x16 tile)
#pragma unroll
    for (int fc = 0; fc < 4; ++fc) {
        const int n  = n0 + wc * 64 + fc * 16 + c;
        const float bb = bias[n];
        const int h  = n / 192;
        const int rem = n - h * 192;
#pragma unroll
        for (int fr = 0; fr < 4; ++fr) {
            const int mb = m0 + wr * 64 + fr * 16 + (quad << 2);
            if constexpr (OMODE == 0) {
#pragma unroll
                for (int r = 0; r < 4; ++r)
                    Cf[(size_t)(mb + r) * N + n] = acc[fr][fc][r] + bb;
            } else {
                if (rem < 128) {
                    const size_t col = h * 128 + rem;
                    const float scale = (rem < 64) ? QSCALE : 1.0f;
#pragma unroll
                    for (int r = 0; r < 4; ++r)
                        QKhi[(size_t)(mb + r) * QKW + col] =
                            (_Float16)((acc[fr][fc][r] + bb) * scale);
                } else {
                    // V2 PV-native layout write (keys s..s+3, feature d)
                    const int d  = rem - 128;          // d = dbase + c, dbase%16==0
                    const int b  = mb >> 11;
                    const int sq = mb & 2047;          // seq, % 4 == 0
                    const int kt = sq >> 6;
                    const int rs = sq & 63;
                    const int gp = rs >> 5;
                    const int hf = (rs >> 4) & 1;
                    const int kq = (rs >> 2) & 3;
                    const int v  = d >> 4;
                    const int cl = d & 15;
                    half4 h4;
#pragma unroll
                    for (int r = 0; r < 4; ++r)
                        h4[r] = (_Float16)(acc[fr][fc][r] + bb);
                    const size_t off =
                        ((((size_t)(h * BATCH + b) * (SEQ / 64) + kt) * 8
                          + (v * 2 + gp)) * 512)
                        + (size_t)(kq * 16 + cl) * 8 + hf * 4;
                    *(half4*)(Vthi + off) = h4;
                }
            }
        }
    }
}

// ---------------------------------------------------------------------------
// MFMA flash attention v12 — unchanged from R10 (passing, <90 us).
// Full-rate PV via concat frags, PV-native V2 (conflict-free b128 reads),
// ones-MFMA l row-sums, max-free exp2 softmax, double-buffered staging.
// ---------------------------------------------------------------------------
__global__ __launch_bounds__(256, 4) void attn_mfma(
    const _Float16* __restrict__ qkhi,
    const _Float16* __restrict__ vthi,
    _Float16* __restrict__ attnf)
{
    __shared__ __align__(16) _Float16 Kf[2][8][512];    // chunk idx = u*2 + ks
    __shared__ __align__(16) _Float16 Vf[2][8][512];    // chunk idx = v*2 + gp

    const int tid  = threadIdx.x;
    const int w    = tid >> 6;
    const int lane = tid & 63;
    const int quad = lane >> 4;
    const int c    = lane & 15;

    const int lin = blockIdx.x;
    const int g   = lin & 7;               // assumed XCD id
    const int s   = lin >> 3;              // 0..127
    const int bh  = g * 8 + (s >> 4);      // 8 bh per XCD
    const int qt  = s & 15;                // 16 q-tiles of 128
    const int b   = bh >> 4, h = bh & 15;
    const int q0  = qt * 128;

    const size_t bSEQ  = (size_t)b * SEQ;
    const int    qcol  = h * 128;
    const int    kcol  = h * 128 + 64;

    // ---- preload Q fragments (B-operand): rows q0 + w*32 + t*16 + c ----
    half8 qh[2][2];
#pragma unroll
    for (int t = 0; t < 2; ++t) {
        const size_t row = (bSEQ + q0 + w * 32 + t * 16 + c) * QKW;
#pragma unroll
        for (int ks = 0; ks < 2; ++ks)
            qh[t][ks] = *(const half8*)(qkhi + row + qcol + ks * 32 + quad * 8);
    }

    f32x4 lacc[2];
    f32x4 oacc[4][2];                       // [v(d-tile)][t]: O^T rows d, col q=c
#pragma unroll
    for (int t = 0; t < 2; ++t) {
        lacc[t] = (f32x4){0.f, 0.f, 0.f, 0.f};
#pragma unroll
        for (int v = 0; v < 4; ++v) oacc[v][t] = (f32x4){0.f, 0.f, 0.f, 0.f};
    }

    const half8 one8 = {(_Float16)1.f, (_Float16)1.f, (_Float16)1.f, (_Float16)1.f,
                        (_Float16)1.f, (_Float16)1.f, (_Float16)1.f, (_Float16)1.f};

    // ---- loop-invariant staging pointers ----
    const int ku0 = w >> 1,       kks0 = w & 1;
    const int ku1 = (4 + w) >> 1, kks1 = (4 + w) & 1;
    const _Float16* kp0 = qkhi + (bSEQ + ku0 * 16 + c) * QKW + kcol + kks0 * 32 + quad * 8;
    const _Float16* kp1 = qkhi + (bSEQ + ku1 * 16 + c) * QKW + kcol + kks1 * 32 + quad * 8;
    // V2: per (h,b,kt) 8 chunks x 512 halves, fully linear staging
    const _Float16* vp0 = vthi + ((size_t)(h * BATCH + b) * (SEQ / 64)) * 4096
                               + (size_t)w * 512 + lane * 8;
    const _Float16* vp1 = vp0 + 4 * 512;

    auto stageKV = [&](int bfs) {
        gld16(kp0, &Kf[bfs][w][0]);
        gld16(kp1, &Kf[bfs][4 + w][0]);
        gld16(vp0, &Vf[bfs][w][0]);
        gld16(vp1, &Vf[bfs][4 + w][0]);
        kp0 += 64 * QKW; kp1 += 64 * QKW; vp0 += 4096; vp1 += 4096;
    };

    stageKV(0);
    int bf = 0;

    for (int kt = 0; kt < SEQ / 64; ++kt) {
        __syncthreads();                       // staged loads for bf complete
        if (kt + 1 < SEQ / 64) stageKV(bf ^ 1);   // prefetch next tile

        // ---- QK^T for BOTH q-tiles per kh chunk (kh read once, 8 b128) ----
        f32x4 sacc[2][4];
        __builtin_amdgcn_s_setprio(1);
#pragma unroll
        for (int u = 0; u < 4; ++u) {
            const half8 kh0 = *(const half8*)&Kf[bf][(u << 1) + 0][lane << 3];
            const half8 kh1 = *(const half8*)&Kf[bf][(u << 1) + 1][lane << 3];
#pragma unroll
            for (int t = 0; t < 2; ++t) {
                f32x4 a = (f32x4){0.f, 0.f, 0.f, 0.f};
                a = mfma16(kh0, qh[t][0], a);
                a = mfma16(kh1, qh[t][1], a);
                sacc[t][u] = a;
            }
        }
        __builtin_amdgcn_s_setprio(0);

        // ---- max-free softmax (exp2 domain): P = 2^s; pack into concat
        //      B-frags pb[t][gp] (elems 0-3 <- u=2gp, elems 4-7 <- u=2gp+1)
        half8 pb[2][2];
#pragma unroll
        for (int t = 0; t < 2; ++t)
#pragma unroll
            for (int gp = 0; gp < 2; ++gp) {
                uint4v wd;
#pragma unroll
                for (int hf = 0; hf < 2; ++hf) {
                    const int u = 2 * gp + hf;
                    const float p0 = exp2x(sacc[t][u][0]);
                    const float p1 = exp2x(sacc[t][u][1]);
                    const float p2 = exp2x(sacc[t][u][2]);
                    const float p3 = exp2x(sacc[t][u][3]);
                    if (hf == 0) { wd.x = pk2(p0, p1); wd.y = pk2(p2, p3); }
                    else         { wd.z = pk2(p0, p1); wd.w = pk2(p2, p3); }
                }
                pb[t][gp] = __builtin_bit_cast(half8, wd);
            }

        // ---- V concat A-frags: ONE b128 per (v,gp), conflict-free ----
        half8 vb[4][2];
#pragma unroll
        for (int v = 0; v < 4; ++v)
#pragma unroll
            for (int gp = 0; gp < 2; ++gp)
                vb[v][gp] = *(const half8*)&Vf[bf][(v << 1) + gp][lane << 3];

        // ---- PV (full-rate 16x16x32) + ones-MFMA l row-sums ----
        __builtin_amdgcn_s_setprio(1);
#pragma unroll
        for (int t = 0; t < 2; ++t) {
#pragma unroll
            for (int v = 0; v < 4; ++v) {
                f32x4 a = oacc[v][t];
                a = mfma16(vb[v][0], pb[t][0], a);
                a = mfma16(vb[v][1], pb[t][1], a);
                oacc[v][t] = a;
            }
            f32x4 l = lacc[t];
            l = mfma16(one8, pb[t][0], l);
            l = mfma16(one8, pb[t][1], l);
            lacc[t] = l;
        }
        __builtin_amdgcn_s_setprio(0);

        bf ^= 1;
    }

    // ---- epilogue: O^T /= l (all rows of lacc equal); write fp16 plane ----
#pragma unroll
    for (int t = 0; t < 2; ++t) {
        const float inv = 1.0f / lacc[t][0];
        const int tok = q0 + w * 32 + t * 16 + c;
#pragma unroll
        for (int v = 0; v < 4; ++v) {
            half4 o;
#pragma unroll
            for (int r = 0; r < 4; ++r) o[r] = (_Float16)(oacc[v][t][r] * inv);
            *(half4*)&attnf[(bSEQ + tok) * EMBED + h * HDIM + v * 16 + (quad << 2)] = o;
        }
    }
}

// ---------------------------------------------------------------------------
// Workspace (~76 MB of 128 MiB):
//   QK plane [8192][2048]             = 33.55 MB
//   V2 plane [16][4][32][8][512]      = 16.78 MB (PV-native chunks)
//   w1 hi    [3072][1024]             =  6.29 MB
//   w2 hi    [1024][1024]             =  2.10 MB
//   attn fp16 [8192][1024]            = 16.78 MB
// x hi plane lives in d_out (16.78 MB), dead before GEMM2 overwrites it.
// ---------------------------------------------------------------------------
extern "C" void kernel_launch(void* const* d_in, const int* in_sizes, int n_in,
                              void* d_out, int out_size, void* d_ws, size_t ws_size,
                              hipStream_t stream)
{
    const float* x     = (const float*)d_in[0];
    const float* qkv_w = (const float*)d_in[1];
    const float* qkv_b = (const float*)d_in[2];
    const float* out_w = (const float*)d_in[3];
    const float* out_b = (const float*)d_in[4];

    _Float16* qkhi  = (_Float16*)d_ws;
    _Float16* vthi  = qkhi  + (size_t)MTOK * QKW;
    _Float16* w1hi  = vthi  + (size_t)NHEAD * HDIM * BATCH * SEQ;
    _Float16* w2hi  = w1hi  + (size_t)THREE_E * EMBED;
    _Float16* attnf = w2hi  + (size_t)EMBED * EMBED;

    _Float16* xhi = (_Float16*)d_out;

    // fused fp32->fp16 pre-pass (single launch)
    tohi3_kernel<<<dim3(12288), 256, 0, stream>>>(x, xhi, qkv_w, w1hi, out_w, w2hi);

    // qkv = x @ qkv_w^T + qkv_b  -> QK plane (Q pre-scaled, exp2 domain) + V2 plane
    gemm_big<1><<<dim3(THREE_E / 256, MTOK / 128), 512, 0, stream>>>(
        xhi, w1hi, qkv_b, nullptr, qkhi, vthi, THREE_E, EMBED);

    // attention -> attn fp16 plane (1024 blocks, XCD-swizzled, 4 blocks/CU)
    attn_mfma<<<dim3(1024), 256, 0, stream>>>(qkhi, vthi, attnf);

    // out = attn @ out_w^T + out_b  -> fp32 d_out
    gemm_big<0><<<dim3(EMBED / 256, MTOK / 128), 512, 0, stream>>>(
        attnf, w2hi, out_b, (float*)d_out, nullptr, nullptr, EMBED, EMBED);
}